// Round 1
// baseline (328.665 us; speedup 1.0000x reference)
//
#include <hip/hip_runtime.h>
#include <stdint.h>

typedef _Float16 f16;
typedef _Float16 f16x4 __attribute__((ext_vector_type(4)));
typedef _Float16 f16x8 __attribute__((ext_vector_type(8)));
typedef float f32x4 __attribute__((ext_vector_type(4)));

#define K_DIM 1600
#define NF_DIM 6400

// ---------- async global->LDS 16B copy (gfx950 global_load_lds_dwordx4) ----------
__device__ __forceinline__ void async_copy16(const void* g, void* l) {
    __builtin_amdgcn_global_load_lds(
        (const __attribute__((address_space(1))) void*)(uintptr_t)g,
        (__attribute__((address_space(3))) void*)(uint32_t)(uintptr_t)l,
        16, 0, 0);
}

// ---------- block-wide max (256 threads = 4 waves) ----------
__device__ __forceinline__ float blockMax(float v, float* sm) {
#pragma unroll
    for (int off = 32; off > 0; off >>= 1)
        v = fmaxf(v, __shfl_down(v, off, 64));
    int wid = threadIdx.x >> 6, lane = threadIdx.x & 63;
    if (lane == 0) sm[wid] = v;
    __syncthreads();
    if (threadIdx.x == 0) {
        float m = sm[0];
        for (int i = 1; i < (int)(blockDim.x >> 6); ++i) m = fmaxf(m, sm[i]);
        sm[0] = m;
    }
    __syncthreads();
    return sm[0];
}

// ---------- per-token activation quant: qx (fp16 ints), ax = 1/(s+1e-6) ----------
__global__ void quant_x_kernel(const float* __restrict__ x, f16* __restrict__ qx,
                               float* __restrict__ ax, int K) {
    __shared__ float sm[4];
    size_t row = blockIdx.x;
    const float* xr = x + row * (size_t)K;
    float m = 0.f;
    int n4 = K >> 2;  // 400
    for (int i = threadIdx.x; i < n4; i += blockDim.x) {
        float4 v = ((const float4*)xr)[i];
        m = fmaxf(fmaxf(fmaxf(fabsf(v.x), fabsf(v.y)), fmaxf(fabsf(v.z), fabsf(v.w))), m);
    }
    m = blockMax(m, sm);
    float s = 127.0f / (m + 1e-6f);
    if (threadIdx.x == 0) ax[row] = 1.0f / (s + 1e-6f);
    f16* qr = qx + row * (size_t)K;
    for (int i = threadIdx.x; i < n4; i += blockDim.x) {
        float4 v = ((const float4*)xr)[i];
        f16x4 q;
        q[0] = (f16)rintf(v.x * s);
        q[1] = (f16)rintf(v.y * s);
        q[2] = (f16)rintf(v.z * s);
        q[3] = (f16)rintf(v.w * s);
        *(f16x4*)&qr[i * 4] = q;
    }
}

// ---------- per-row weight scale: sw[k] = 127/(maxabs+1e-6) ----------
__global__ void wscale_kernel(const float* __restrict__ w, float* __restrict__ sw, int NF) {
    __shared__ float sm[4];
    size_t k = blockIdx.x;
    const float* wr = w + k * (size_t)NF;
    float m = 0.f;
    int n4 = NF >> 2;  // 1600
    for (int i = threadIdx.x; i < n4; i += blockDim.x) {
        float4 v = ((const float4*)wr)[i];
        m = fmaxf(fmaxf(fmaxf(fabsf(v.x), fabsf(v.y)), fmaxf(fabsf(v.z), fabsf(v.w))), m);
    }
    m = blockMax(m, sm);
    if (threadIdx.x == 0) sw[k] = 127.0f / (m + 1e-6f);
}

// ---------- quantize + transpose weight -> wqt[N][K] fp16 (64x64 tiles) ----------
__global__ void wtq_kernel(const float* __restrict__ w, const float* __restrict__ sw,
                           f16* __restrict__ wqt, int K, int NF) {
    __shared__ f16 t[64][80];  // 160B row stride: 16B-aligned vector reads
    int k0 = blockIdx.x * 64;
    int f0 = blockIdx.y * 64;
    int tid = threadIdx.x;
    int rr = tid >> 4;
    int cc = (tid & 15) << 2;
#pragma unroll
    for (int i = 0; i < 4; ++i) {
        int r = rr + i * 16;
        float s = sw[k0 + r];
        float inv = 1.0f / (s + 1e-6f);
        float4 v = *(const float4*)&w[(size_t)(k0 + r) * NF + f0 + cc];
        t[cc + 0][r] = (f16)(rintf(v.x * s) * inv);
        t[cc + 1][r] = (f16)(rintf(v.y * s) * inv);
        t[cc + 2][r] = (f16)(rintf(v.z * s) * inv);
        t[cc + 3][r] = (f16)(rintf(v.w * s) * inv);
    }
    __syncthreads();
    int fr = tid >> 2;
    int ch = (tid & 3) << 4;  // 16 f16 = 32B per thread
    const float4* src = (const float4*)&t[fr][ch];
    float4* dst = (float4*)&wqt[(size_t)(f0 + fr) * K + k0 + ch];
    dst[0] = src[0];
    dst[1] = src[1];
}

// ---------- GEMM: C[M][N] = (qx[M][K] fp16) x (wqt[N][K] fp16)^T * ax[m] + bias[n] ----------
// 128x128 tile, BK=64, 256 threads = 4 waves (2x2 of 64x64), mfma_f32_16x16x32_f16
__global__ __launch_bounds__(256) void gemm_f16(
    const f16* __restrict__ A,    // [M][K]
    const f16* __restrict__ Bt,   // [N][K]
    const float* __restrict__ ax, // [M]
    const float* __restrict__ bias,
    float* __restrict__ C,        // [M][N]
    int M, int N, int K) {
    __shared__ f16 As[128 * 64];
    __shared__ f16 Bs[128 * 64];

    int nTn = N / 128;  // 50
    int nwg = gridDim.x;
    int bid = blockIdx.x;
    // bijective XCD swizzle (nwg % 8 == 0)
    int cpx = nwg >> 3;
    int swz = (bid & 7) * cpx + (bid >> 3);
    int tm = swz / nTn, tn = swz % nTn;
    size_t m0 = (size_t)tm * 128, n0 = (size_t)tn * 128;

    int tid = threadIdx.x;
    int lane = tid & 63;
    int wv = tid >> 6;
    int wm = (wv >> 1) * 64, wn = (wv & 1) * 64;
    int lr = lane & 15, lg = lane >> 4;

    f32x4 acc[4][4] = {};

    const int nk = K / 64;  // 25
    for (int kt = 0; kt < nk; ++kt) {
        __syncthreads();  // previous compute done before overwriting LDS
        size_t k0 = (size_t)kt * 64;
#pragma unroll
        for (int it = 0; it < 4; ++it) {
            int idx = it * 256 + tid;
            int r = idx >> 3;             // tile row
            int cb = (idx & 7) * 16;      // byte offset in 128B row
            const char* srcA = (const char*)(A + ((m0 + r) * (size_t)K + k0)) + cb;
            async_copy16(srcA, (char*)As + idx * 16);
            const char* srcB = (const char*)(Bt + ((n0 + r) * (size_t)K + k0)) + cb;
            async_copy16(srcB, (char*)Bs + idx * 16);
        }
        asm volatile("s_waitcnt vmcnt(0)" ::: "memory");
        __syncthreads();

#pragma unroll
        for (int kk = 0; kk < 2; ++kk) {
            f16x8 a[4], b[4];
#pragma unroll
            for (int mi = 0; mi < 4; ++mi)
                a[mi] = *(const f16x8*)&As[(wm + mi * 16 + lr) * 64 + kk * 32 + lg * 8];
#pragma unroll
            for (int ni = 0; ni < 4; ++ni)
                b[ni] = *(const f16x8*)&Bs[(wn + ni * 16 + lr) * 64 + kk * 32 + lg * 8];
#pragma unroll
            for (int mi = 0; mi < 4; ++mi)
#pragma unroll
                for (int ni = 0; ni < 4; ++ni)
                    acc[mi][ni] = __builtin_amdgcn_mfma_f32_16x16x32_f16(a[mi], b[ni], acc[mi][ni], 0, 0, 0);
        }
    }

    // epilogue: C = acc * ax[m] + bias[n]
#pragma unroll
    for (int mi = 0; mi < 4; ++mi) {
#pragma unroll
        for (int j = 0; j < 4; ++j) {
            size_t mg = m0 + wm + mi * 16 + lg * 4 + j;
            float axv = ax[mg];
            float* crow = C + mg * (size_t)N + n0 + wn;
#pragma unroll
            for (int ni = 0; ni < 4; ++ni) {
                int ng = ni * 16 + lr;
                crow[ng] = acc[mi][ni][j] * axv + bias[n0 + wn + ng];
            }
        }
    }
}

extern "C" void kernel_launch(void* const* d_in, const int* in_sizes, int n_in,
                              void* d_out, int out_size, void* d_ws, size_t ws_size,
                              hipStream_t stream) {
    const float* x = (const float*)d_in[0];
    const float* w = (const float*)d_in[1];
    const float* bias = (const float*)d_in[2];
    float* out = (float*)d_out;

    const int K = K_DIM;    // 1600
    const int NF = NF_DIM;  // 6400
    const int M = in_sizes[0] / K;  // 8192

    char* ws = (char*)d_ws;
    f16* qx = (f16*)ws;                                     // M*K*2   = 26,214,400 B
    f16* wqt = (f16*)(ws + (size_t)M * K * 2);              // NF*K*2  = 20,480,000 B
    float* ax = (float*)(ws + (size_t)M * K * 2 + (size_t)NF * K * 2);  // M*4
    float* sw = ax + M;                                     // K*4

    quant_x_kernel<<<M, 256, 0, stream>>>(x, qx, ax, K);
    wscale_kernel<<<K, 256, 0, stream>>>(w, sw, NF);
    wtq_kernel<<<dim3(K / 64, NF / 64), 256, 0, stream>>>(w, sw, wqt, K, NF);
    gemm_f16<<<(M / 128) * (NF / 128), 256, 0, stream>>>(qx, wqt, ax, bias, out, M, NF, K);
}

// Round 2
// 265.304 us; speedup vs baseline: 1.2388x; 1.2388x over previous
//
#include <hip/hip_runtime.h>
#include <stdint.h>

typedef _Float16 f16;
typedef _Float16 f16x4 __attribute__((ext_vector_type(4)));
typedef _Float16 f16x8 __attribute__((ext_vector_type(8)));
typedef float f32x4 __attribute__((ext_vector_type(4)));

#define K_DIM 1600
#define NF_DIM 6400
#define KPAD 1664   // 26 tiles of 64
#define NKT 26

// ---------- async global->LDS 16B copy ----------
__device__ __forceinline__ void async_copy16(const void* g, void* l) {
    __builtin_amdgcn_global_load_lds(
        (const __attribute__((address_space(1))) void*)(uintptr_t)g,
        (__attribute__((address_space(3))) void*)(uint32_t)(uintptr_t)l,
        16, 0, 0);
}

// ---------- block-wide max (256 threads = 4 waves) ----------
__device__ __forceinline__ float blockMax(float v, float* sm) {
#pragma unroll
    for (int off = 32; off > 0; off >>= 1)
        v = fmaxf(v, __shfl_down(v, off, 64));
    int wid = threadIdx.x >> 6, lane = threadIdx.x & 63;
    if (lane == 0) sm[wid] = v;
    __syncthreads();
    if (threadIdx.x == 0) {
        float m = sm[0];
        for (int i = 1; i < (int)(blockDim.x >> 6); ++i) m = fmaxf(m, sm[i]);
        sm[0] = m;
    }
    __syncthreads();
    return sm[0];
}

// ---------- per-token activation quant: qx (fp16 ints, KPAD stride), ax ----------
__global__ void quant_x_kernel(const float* __restrict__ x, f16* __restrict__ qx,
                               float* __restrict__ ax) {
    __shared__ float sm[4];
    size_t row = blockIdx.x;
    const float* xr = x + row * (size_t)K_DIM;
    float m = 0.f;
    const int n4 = K_DIM >> 2;  // 400
    for (int i = threadIdx.x; i < n4; i += blockDim.x) {
        float4 v = ((const float4*)xr)[i];
        m = fmaxf(fmaxf(fmaxf(fabsf(v.x), fabsf(v.y)), fmaxf(fabsf(v.z), fabsf(v.w))), m);
    }
    m = blockMax(m, sm);
    float s = 127.0f / (m + 1e-6f);
    if (threadIdx.x == 0) ax[row] = 1.0f / (s + 1e-6f);
    f16* qr = qx + row * (size_t)KPAD;
    for (int i = threadIdx.x; i < n4; i += blockDim.x) {
        float4 v = ((const float4*)xr)[i];
        f16x4 q;
        q[0] = (f16)rintf(v.x * s);
        q[1] = (f16)rintf(v.y * s);
        q[2] = (f16)rintf(v.z * s);
        q[3] = (f16)rintf(v.w * s);
        *(f16x4*)&qr[i * 4] = q;
    }
    if (threadIdx.x < 16) {  // zero-pad cols [1600,1664)
        f16x4 z = {};
        *(f16x4*)&qr[K_DIM + threadIdx.x * 4] = z;
    }
}

// ---------- per-row weight scale ----------
__global__ void wscale_kernel(const float* __restrict__ w, float* __restrict__ sw) {
    __shared__ float sm[4];
    size_t k = blockIdx.x;
    const float* wr = w + k * (size_t)NF_DIM;
    float m = 0.f;
    const int n4 = NF_DIM >> 2;
    for (int i = threadIdx.x; i < n4; i += blockDim.x) {
        float4 v = ((const float4*)wr)[i];
        m = fmaxf(fmaxf(fmaxf(fabsf(v.x), fabsf(v.y)), fmaxf(fabsf(v.z), fabsf(v.w))), m);
    }
    m = blockMax(m, sm);
    if (threadIdx.x == 0) sw[k] = 127.0f / (m + 1e-6f);
}

// ---------- quantize + transpose weight -> wqt[N][KPAD] fp16 ----------
__global__ void wtq_kernel(const float* __restrict__ w, const float* __restrict__ sw,
                           f16* __restrict__ wqt) {
    __shared__ f16 t[64][80];
    int k0 = blockIdx.x * 64;
    int f0 = blockIdx.y * 64;
    int tid = threadIdx.x;
    if (k0 >= K_DIM) {  // pad tiles: pure zeros (block-uniform branch)
        int fr = tid >> 2;
        int ch = (tid & 3) << 4;
        float4 z = {};
        float4* dst = (float4*)&wqt[(size_t)(f0 + fr) * KPAD + k0 + ch];
        dst[0] = z;
        dst[1] = z;
        return;
    }
    int rr = tid >> 4;
    int cc = (tid & 15) << 2;
#pragma unroll
    for (int i = 0; i < 4; ++i) {
        int r = rr + i * 16;
        float s = sw[k0 + r];
        float inv = 1.0f / (s + 1e-6f);
        float4 v = *(const float4*)&w[(size_t)(k0 + r) * NF_DIM + f0 + cc];
        t[cc + 0][r] = (f16)(rintf(v.x * s) * inv);
        t[cc + 1][r] = (f16)(rintf(v.y * s) * inv);
        t[cc + 2][r] = (f16)(rintf(v.z * s) * inv);
        t[cc + 3][r] = (f16)(rintf(v.w * s) * inv);
    }
    __syncthreads();
    int fr = tid >> 2;
    int ch = (tid & 3) << 4;
    const float4* src = (const float4*)&t[fr][ch];
    float4* dst = (float4*)&wqt[(size_t)(f0 + fr) * KPAD + k0 + ch];
    dst[0] = src[0];
    dst[1] = src[1];
}

// ---------- 256x256 multi-phase GEMM ----------
// C[M][N] = (qx[M][KPAD]) x (wqt[N][KPAD])^T * ax[m] + bias[n]
// 8 waves (2M x 4N), per-wave 128x64 output, BK=64, dbuf 128KiB LDS,
// 4 phases/K-tile, counted vmcnt(8), XOR-swizzled LDS (both-sides).
__global__ __launch_bounds__(512, 1) void gemm256(
    const f16* __restrict__ A,    // [M][KPAD]
    const f16* __restrict__ Bt,   // [N][KPAD]
    const float* __restrict__ ax,
    const float* __restrict__ bias,
    float* __restrict__ C, int M, int N) {
    extern __shared__ char lds[];
    // buf b: lds + b*65536 ; A region [256][64]f16 at +0, B region at +32768

    const int tid = threadIdx.x;
    const int lane = tid & 63;
    const int wv = tid >> 6;   // 0..7
    const int wm = wv >> 2;    // 0..1
    const int wn = wv & 3;     // 0..3
    const int lr = lane & 15;
    const int lg = lane >> 4;

    const int nTn = N / 256;            // 25
    const int bid = blockIdx.x;
    const int cpx = gridDim.x >> 3;     // 100 (800 % 8 == 0 -> bijective)
    const int swz = (bid & 7) * cpx + (bid >> 3);
    const int tm = swz / nTn, tn = swz % nTn;
    const size_t m0 = (size_t)tm * 256, n0 = (size_t)tn * 256;

    // staging constants: per-lane inverse-swizzled source slot
    const int srow8 = lane >> 3;                    // row within 8-row group
    const int sslot = (lane & 7) ^ srow8;           // pre-swizzled source chunk

    // stage one half-tile (128 rows x 64 cols f16) of `mat` into LDS at lhalf
#define STAGE_HALF(mat, row0, kb, lhalf)                                              \
    {                                                                                 \
        _Pragma("unroll") for (int j = 0; j < 2; ++j) {                               \
            int L = (wv * 2 + j) * 1024 + lane * 16;                                  \
            int row = wv * 16 + j * 8 + srow8;                                        \
            const char* g = (const char*)((mat) + ((row0) + row) * (size_t)KPAD) +    \
                            (kb) + sslot * 16;                                        \
            async_copy16(g, (lhalf) + L);                                             \
        }                                                                             \
    }

#define STAGE_TILE(kidx, buf)                                   \
    {                                                           \
        int kb_ = (kidx) * 128;                                 \
        STAGE_HALF(A, m0, kb_, (buf));                          \
        STAGE_HALF(A, m0 + 128, kb_, (buf) + 16384);            \
        STAGE_HALF(Bt, n0, kb_, (buf) + 32768);                 \
        STAGE_HALF(Bt, n0 + 128, kb_, (buf) + 49152);           \
    }

    // swizzled fragment read: row-major [256][64]f16, 16B chunks XOR'd by row&7
#define LDF(base, row, s) \
    (*(const f16x8*)((base) + (row) * 128 + ((((s) ^ ((row) & 7))) << 4)))

    f32x4 acc[8][4] = {};

    // ---- prologue: stage K-tiles 0,1 ----
    STAGE_TILE(0, lds);
    STAGE_TILE(1, lds + 65536);
    asm volatile("s_waitcnt vmcnt(8)" ::: "memory");  // tile 0 landed
    asm volatile("s_barrier" ::: "memory");

    for (int kt = 0; kt < NKT; ++kt) {
        char* buf = lds + (kt & 1) * 65536;
        const char* Ab = buf;
        const char* Bb = buf + 32768;
        int pf = (kt + 2 < NKT) ? kt + 2 : NKT - 1;  // clamped prefetch src index

        f16x8 alo[4][2], ahi[4][2], bA[2][2], bB[2][2];

        // ===== PH0: read alo + bA ; MFMA (m-lo x n-lo) =====
#pragma unroll
        for (int mi = 0; mi < 4; ++mi)
#pragma unroll
            for (int kk = 0; kk < 2; ++kk)
                alo[mi][kk] = LDF(Ab, wm * 128 + mi * 16 + lr, kk * 4 + lg);
#pragma unroll
        for (int ni = 0; ni < 2; ++ni)
#pragma unroll
            for (int kk = 0; kk < 2; ++kk)
                bA[ni][kk] = LDF(Bb, wn * 64 + ni * 16 + lr, kk * 4 + lg);
        asm volatile("s_barrier" ::: "memory");
        asm volatile("s_waitcnt lgkmcnt(0)" ::: "memory");
        __builtin_amdgcn_sched_barrier(0);
        __builtin_amdgcn_s_setprio(1);
#pragma unroll
        for (int mi = 0; mi < 4; ++mi)
#pragma unroll
            for (int ni = 0; ni < 2; ++ni)
#pragma unroll
                for (int kk = 0; kk < 2; ++kk)
                    acc[mi][ni] = __builtin_amdgcn_mfma_f32_16x16x32_f16(
                        alo[mi][kk], bA[ni][kk], acc[mi][ni], 0, 0, 0);
        __builtin_amdgcn_s_setprio(0);
        asm volatile("s_barrier" ::: "memory");

        // ===== PH1: read ahi ; MFMA (m-hi x n-lo) =====
#pragma unroll
        for (int mi = 0; mi < 4; ++mi)
#pragma unroll
            for (int kk = 0; kk < 2; ++kk)
                ahi[mi][kk] = LDF(Ab, wm * 128 + 64 + mi * 16 + lr, kk * 4 + lg);
        asm volatile("s_barrier" ::: "memory");
        asm volatile("s_waitcnt lgkmcnt(0)" ::: "memory");
        __builtin_amdgcn_sched_barrier(0);
        __builtin_amdgcn_s_setprio(1);
#pragma unroll
        for (int mi = 0; mi < 4; ++mi)
#pragma unroll
            for (int ni = 0; ni < 2; ++ni)
#pragma unroll
                for (int kk = 0; kk < 2; ++kk)
                    acc[4 + mi][ni] = __builtin_amdgcn_mfma_f32_16x16x32_f16(
                        ahi[mi][kk], bA[ni][kk], acc[4 + mi][ni], 0, 0, 0);
        __builtin_amdgcn_s_setprio(0);
        asm volatile("s_barrier" ::: "memory");

        // ===== PH2: read bB ; MFMA (m-hi x n-hi) =====
#pragma unroll
        for (int ni = 0; ni < 2; ++ni)
#pragma unroll
            for (int kk = 0; kk < 2; ++kk)
                bB[ni][kk] = LDF(Bb, wn * 64 + 32 + ni * 16 + lr, kk * 4 + lg);
        asm volatile("s_barrier" ::: "memory");
        asm volatile("s_waitcnt lgkmcnt(0)" ::: "memory");
        __builtin_amdgcn_sched_barrier(0);
        __builtin_amdgcn_s_setprio(1);
#pragma unroll
        for (int mi = 0; mi < 4; ++mi)
#pragma unroll
            for (int ni = 0; ni < 2; ++ni)
#pragma unroll
                for (int kk = 0; kk < 2; ++kk)
                    acc[4 + mi][2 + ni] = __builtin_amdgcn_mfma_f32_16x16x32_f16(
                        ahi[mi][kk], bB[ni][kk], acc[4 + mi][2 + ni], 0, 0, 0);
        __builtin_amdgcn_s_setprio(0);
        asm volatile("s_barrier" ::: "memory");

        // ===== PH3: stage tile kt+2 into buf (consumed); vmcnt(8); MFMA (m-lo x n-hi) =====
        STAGE_TILE(pf, buf);
        asm volatile("s_waitcnt vmcnt(8)" ::: "memory");  // tile kt+1 landed; kt+2 in flight
        asm volatile("s_barrier" ::: "memory");
        __builtin_amdgcn_sched_barrier(0);
        __builtin_amdgcn_s_setprio(1);
#pragma unroll
        for (int mi = 0; mi < 4; ++mi)
#pragma unroll
            for (int ni = 0; ni < 2; ++ni)
#pragma unroll
                for (int kk = 0; kk < 2; ++kk)
                    acc[mi][2 + ni] = __builtin_amdgcn_mfma_f32_16x16x32_f16(
                        alo[mi][kk], bB[ni][kk], acc[mi][2 + ni], 0, 0, 0);
        __builtin_amdgcn_s_setprio(0);
        asm volatile("s_barrier" ::: "memory");
    }
    asm volatile("s_waitcnt vmcnt(0)" ::: "memory");  // drain clamped tail prefetches

    // ---- epilogue: C = acc * ax[m] + bias[n] ----
#pragma unroll
    for (int mi = 0; mi < 8; ++mi) {
#pragma unroll
        for (int j = 0; j < 4; ++j) {
            size_t mg = m0 + wm * 128 + mi * 16 + lg * 4 + j;
            float axv = ax[mg];
            float* crow = C + mg * (size_t)N + n0 + wn * 64;
#pragma unroll
            for (int ni = 0; ni < 4; ++ni) {
                int ng = ni * 16 + lr;
                crow[ng] = acc[mi][ni][j] * axv + bias[n0 + wn * 64 + ng];
            }
        }
    }
#undef STAGE_HALF
#undef STAGE_TILE
#undef LDF
}

extern "C" void kernel_launch(void* const* d_in, const int* in_sizes, int n_in,
                              void* d_out, int out_size, void* d_ws, size_t ws_size,
                              hipStream_t stream) {
    const float* x = (const float*)d_in[0];
    const float* w = (const float*)d_in[1];
    const float* bias = (const float*)d_in[2];
    float* out = (float*)d_out;

    const int M = in_sizes[0] / K_DIM;  // 8192
    const int N = NF_DIM;               // 6400

    char* ws = (char*)d_ws;
    f16* qx = (f16*)ws;                                        // M*KPAD*2
    f16* wqt = (f16*)(ws + (size_t)M * KPAD * 2);              // N*KPAD*2
    float* ax = (float*)(ws + (size_t)M * KPAD * 2 + (size_t)N * KPAD * 2);
    float* sw = ax + M;

    quant_x_kernel<<<M, 256, 0, stream>>>(x, qx, ax);
    wscale_kernel<<<K_DIM, 256, 0, stream>>>(w, sw);
    wtq_kernel<<<dim3(KPAD / 64, NF_DIM / 64), 256, 0, stream>>>(w, sw, wqt);

    (void)hipFuncSetAttribute((const void*)gemm256,
                              hipFuncAttributeMaxDynamicSharedMemorySize, 131072);
    gemm256<<<(M / 256) * (N / 256), 512, 131072, stream>>>(qx, wqt, ax, bias, out, M, N);
}

// Round 3
// 262.850 us; speedup vs baseline: 1.2504x; 1.0093x over previous
//
#include <hip/hip_runtime.h>
#include <stdint.h>

typedef _Float16 f16;
typedef _Float16 f16x4 __attribute__((ext_vector_type(4)));
typedef _Float16 f16x8 __attribute__((ext_vector_type(8)));
typedef float f32x4 __attribute__((ext_vector_type(4)));

#define K_DIM 1600
#define NF_DIM 6400
#define KPAD 1664   // 26 tiles of 64
#define NKT 26

// ---------- async global->LDS 16B copy ----------
__device__ __forceinline__ void async_copy16(const void* g, void* l) {
    __builtin_amdgcn_global_load_lds(
        (const __attribute__((address_space(1))) void*)(uintptr_t)g,
        (__attribute__((address_space(3))) void*)(uint32_t)(uintptr_t)l,
        16, 0, 0);
}

// ---------- block-wide max (256 threads = 4 waves) ----------
__device__ __forceinline__ float blockMax(float v, float* sm) {
#pragma unroll
    for (int off = 32; off > 0; off >>= 1)
        v = fmaxf(v, __shfl_down(v, off, 64));
    int wid = threadIdx.x >> 6, lane = threadIdx.x & 63;
    if (lane == 0) sm[wid] = v;
    __syncthreads();
    if (threadIdx.x == 0) {
        float m = sm[0];
        for (int i = 1; i < (int)(blockDim.x >> 6); ++i) m = fmaxf(m, sm[i]);
        sm[0] = m;
    }
    __syncthreads();
    return sm[0];
}

// ---------- per-token activation quant: qx (fp16 ints, KPAD stride), ax ----------
__global__ void quant_x_kernel(const float* __restrict__ x, f16* __restrict__ qx,
                               float* __restrict__ ax) {
    __shared__ float sm[4];
    size_t row = blockIdx.x;
    const float* xr = x + row * (size_t)K_DIM;
    float m = 0.f;
    const int n4 = K_DIM >> 2;  // 400
    for (int i = threadIdx.x; i < n4; i += blockDim.x) {
        float4 v = ((const float4*)xr)[i];
        m = fmaxf(fmaxf(fmaxf(fabsf(v.x), fabsf(v.y)), fmaxf(fabsf(v.z), fabsf(v.w))), m);
    }
    m = blockMax(m, sm);
    float s = 127.0f / (m + 1e-6f);
    if (threadIdx.x == 0) ax[row] = 1.0f / (s + 1e-6f);
    f16* qr = qx + row * (size_t)KPAD;
    for (int i = threadIdx.x; i < n4; i += blockDim.x) {
        float4 v = ((const float4*)xr)[i];
        f16x4 q;
        q[0] = (f16)rintf(v.x * s);
        q[1] = (f16)rintf(v.y * s);
        q[2] = (f16)rintf(v.z * s);
        q[3] = (f16)rintf(v.w * s);
        *(f16x4*)&qr[i * 4] = q;
    }
    if (threadIdx.x < 16) {  // zero-pad cols [1600,1664)
        f16x4 z = {};
        *(f16x4*)&qr[K_DIM + threadIdx.x * 4] = z;
    }
}

// ---------- per-row weight scale ----------
__global__ void wscale_kernel(const float* __restrict__ w, float* __restrict__ sw) {
    __shared__ float sm[4];
    size_t k = blockIdx.x;
    const float* wr = w + k * (size_t)NF_DIM;
    float m = 0.f;
    const int n4 = NF_DIM >> 2;
    for (int i = threadIdx.x; i < n4; i += blockDim.x) {
        float4 v = ((const float4*)wr)[i];
        m = fmaxf(fmaxf(fmaxf(fabsf(v.x), fabsf(v.y)), fmaxf(fabsf(v.z), fabsf(v.w))), m);
    }
    m = blockMax(m, sm);
    if (threadIdx.x == 0) sw[k] = 127.0f / (m + 1e-6f);
}

// ---------- quantize + transpose weight -> wqt[N][KPAD] fp16 ----------
__global__ void wtq_kernel(const float* __restrict__ w, const float* __restrict__ sw,
                           f16* __restrict__ wqt) {
    __shared__ f16 t[64][80];
    int k0 = blockIdx.x * 64;
    int f0 = blockIdx.y * 64;
    int tid = threadIdx.x;
    if (k0 >= K_DIM) {  // pad tiles: pure zeros (block-uniform branch)
        int fr = tid >> 2;
        int ch = (tid & 3) << 4;
        float4 z = {};
        float4* dst = (float4*)&wqt[(size_t)(f0 + fr) * KPAD + k0 + ch];
        dst[0] = z;
        dst[1] = z;
        return;
    }
    int rr = tid >> 4;
    int cc = (tid & 15) << 2;
#pragma unroll
    for (int i = 0; i < 4; ++i) {
        int r = rr + i * 16;
        float s = sw[k0 + r];
        float inv = 1.0f / (s + 1e-6f);
        float4 v = *(const float4*)&w[(size_t)(k0 + r) * NF_DIM + f0 + cc];
        t[cc + 0][r] = (f16)(rintf(v.x * s) * inv);
        t[cc + 1][r] = (f16)(rintf(v.y * s) * inv);
        t[cc + 2][r] = (f16)(rintf(v.z * s) * inv);
        t[cc + 3][r] = (f16)(rintf(v.w * s) * inv);
    }
    __syncthreads();
    int fr = tid >> 2;
    int ch = (tid & 3) << 4;
    const float4* src = (const float4*)&t[fr][ch];
    float4* dst = (float4*)&wqt[(size_t)(f0 + fr) * KPAD + k0 + ch];
    dst[0] = src[0];
    dst[1] = src[1];
}

// ---------- 256x256 8-phase GEMM (m201 schedule) ----------
// C[M][N] = qx[M][KPAD] x (wqt[N][KPAD])^T * ax[m] + bias[n]
// 8 waves (2M x 4N), per-wave 128x64 out, BK=64, 2 K-tiles/iter,
// 8 phases/iter, 1 half-tile staged per phase, vmcnt(4) at PH4/PH8 only.
__global__ __launch_bounds__(512, 1) void gemm256(
    const f16* __restrict__ A,    // [M][KPAD]
    const f16* __restrict__ Bt,   // [N][KPAD]
    const float* __restrict__ ax,
    const float* __restrict__ bias,
    float* __restrict__ C, int M, int N) {
    extern __shared__ char lds[];
    // buf b at lds + b*65536: A[256][64]f16 at +0 (A-lo rows 0-127, A-hi 128-255),
    //                         B[256][64]f16 at +32768 (B-lo, B-hi)

    const int tid = threadIdx.x;
    const int lane = tid & 63;
    const int wv = tid >> 6;   // 0..7
    const int wm = wv >> 2;    // 0..1  (M half)
    const int wn = wv & 3;     // 0..3  (N quarter)
    const int lr = lane & 15;
    const int lg = lane >> 4;

    const int nTn = N / 256;            // 25
    const int bid = blockIdx.x;
    const int cpx = gridDim.x >> 3;     // 100 (800 % 8 == 0 -> bijective)
    const int swz = (bid & 7) * cpx + (bid >> 3);
    const int tm = swz / nTn, tn = swz % nTn;
    const size_t m0 = (size_t)tm * 256, n0 = (size_t)tn * 256;

    // staging: per-lane inverse-swizzled source chunk
    const int srow8 = lane >> 3;
    const int sslot = (lane & 7) ^ srow8;

    // stage one half-tile (128 rows x 64 cols f16): 2 gloads/thread
#define STAGE_HALF(mat, grow0, kbyte, ldst)                                          \
    {                                                                                \
        _Pragma("unroll") for (int j_ = 0; j_ < 2; ++j_) {                           \
            int L_ = (wv * 2 + j_) * 1024 + lane * 16;                               \
            int row_ = wv * 16 + j_ * 8 + srow8;                                     \
            const char* g_ = (const char*)((mat) + ((grow0) + row_) * (size_t)KPAD)  \
                             + (kbyte) + sslot * 16;                                 \
            async_copy16(g_, (ldst) + L_);                                           \
        }                                                                            \
    }
#define ST_ALO(buf, t) STAGE_HALF(A,  m0,       (t) * 128, (buf))
#define ST_AHI(buf, t) STAGE_HALF(A,  m0 + 128, (t) * 128, (buf) + 16384)
#define ST_BLO(buf, t) STAGE_HALF(Bt, n0,       (t) * 128, (buf) + 32768)
#define ST_BHI(buf, t) STAGE_HALF(Bt, n0 + 128, (t) * 128, (buf) + 49152)

    // swizzled fragment read: [256][64]f16, 16B chunks XOR'd by row&7
#define LDF(base, row, s) \
    (*(const f16x8*)((base) + (row) * 128 + ((((s) ^ ((row) & 7))) << 4)))

#define RD_ALO(Ab)                                                           \
    { _Pragma("unroll") for (int mi_ = 0; mi_ < 4; ++mi_)                    \
      _Pragma("unroll") for (int kk_ = 0; kk_ < 2; ++kk_)                    \
          alo[mi_][kk_] = LDF((Ab), wm * 128 + mi_ * 16 + lr, kk_ * 4 + lg); }
#define RD_AHI(Ab)                                                           \
    { _Pragma("unroll") for (int mi_ = 0; mi_ < 4; ++mi_)                    \
      _Pragma("unroll") for (int kk_ = 0; kk_ < 2; ++kk_)                    \
          ahi[mi_][kk_] = LDF((Ab), wm * 128 + 64 + mi_ * 16 + lr, kk_ * 4 + lg); }
#define RD_BLO(Bb)                                                           \
    { _Pragma("unroll") for (int ni_ = 0; ni_ < 2; ++ni_)                    \
      _Pragma("unroll") for (int kk_ = 0; kk_ < 2; ++kk_)                    \
          blo[ni_][kk_] = LDF((Bb), wn * 64 + ni_ * 16 + lr, kk_ * 4 + lg); }
#define RD_BHI(Bb)                                                           \
    { _Pragma("unroll") for (int ni_ = 0; ni_ < 2; ++ni_)                    \
      _Pragma("unroll") for (int kk_ = 0; kk_ < 2; ++kk_)                    \
          bhi[ni_][kk_] = LDF((Bb), wn * 64 + 32 + ni_ * 16 + lr, kk_ * 4 + lg); }

#define BARRIER __builtin_amdgcn_s_barrier()
#define LGKM0 asm volatile("s_waitcnt lgkmcnt(0)" ::: "memory")
#define SB0 __builtin_amdgcn_sched_barrier(0)
#define VM4 asm volatile("s_waitcnt vmcnt(4)" ::: "memory")

#define MF(AF, BF, R0, C0)                                                        \
    {                                                                             \
        __builtin_amdgcn_s_setprio(1);                                            \
        _Pragma("unroll") for (int mi_ = 0; mi_ < 4; ++mi_)                       \
        _Pragma("unroll") for (int ni_ = 0; ni_ < 2; ++ni_)                       \
        _Pragma("unroll") for (int kk_ = 0; kk_ < 2; ++kk_)                       \
            acc[(R0) + mi_][(C0) + ni_] = __builtin_amdgcn_mfma_f32_16x16x32_f16( \
                AF[mi_][kk_], BF[ni_][kk_], acc[(R0) + mi_][(C0) + ni_], 0, 0, 0);\
        __builtin_amdgcn_s_setprio(0);                                            \
    }

    f32x4 acc[8][4] = {};
    char* buf0 = lds;
    char* buf1 = lds + 65536;
    const char* Ab0 = buf0;
    const char* Bb0 = buf0 + 32768;
    const char* Ab1 = buf1;
    const char* Bb1 = buf1 + 32768;

    // ---- prologue: tile0 full + tile1 B halves (A halves staged by PH1/PH2 of i=0) ----
    ST_ALO(buf0, 0);
    ST_AHI(buf0, 0);
    ST_BLO(buf0, 0);
    ST_BHI(buf0, 0);
    ST_BLO(buf1, 1);
    ST_BHI(buf1, 1);
    VM4;  // tile0's 8 loads retired; tile1's B (4) may remain in flight
    BARRIER;

    for (int i = 0; i < NKT / 2; ++i) {
        const int t1s = 2 * i + 1;
        const int tp2 = (2 * i + 2 < NKT) ? 2 * i + 2 : NKT - 1;  // clamped (freed halves, never read)
        const int tp3 = (2 * i + 3 < NKT) ? 2 * i + 3 : NKT - 1;
        f16x8 alo[4][2], ahi[4][2], blo[2][2], bhi[2][2];

        // ===== PH1: Q0(t0)=alo·blo ; stage A-lo(2i+1)->buf1 =====
        RD_ALO(Ab0);
        RD_BLO(Bb0);
        ST_ALO(buf1, t1s);
        BARRIER; LGKM0; SB0;
        MF(alo, blo, 0, 0);
        BARRIER;

        // ===== PH2: Q3(t0)=alo·bhi ; stage A-hi(2i+1)->buf1 =====
        RD_BHI(Bb0);
        ST_AHI(buf1, t1s);
        BARRIER; LGKM0; SB0;
        MF(alo, bhi, 0, 2);
        BARRIER;

        // ===== PH3: Q1(t0)=ahi·blo ; stage B-lo(2i+2)->buf0 (B freed after PH2) =====
        RD_AHI(Ab0);
        ST_BLO(buf0, tp2);
        BARRIER; LGKM0; SB0;
        MF(ahi, blo, 4, 0);
        BARRIER;

        // ===== PH4: Q2(t0)=ahi·bhi ; stage B-hi(2i+2)->buf0 ; vmcnt(4) =====
        ST_BHI(buf0, tp2);
        VM4;  // retires through tile(2i+1)'s A halves -> buf1 complete for PH5
        BARRIER; SB0;
        MF(ahi, bhi, 4, 2);
        BARRIER;

        // ===== PH5: Q0(t1) ; stage A-lo(2i+2)->buf0 (A freed after PH3) =====
        RD_ALO(Ab1);
        RD_BLO(Bb1);
        ST_ALO(buf0, tp2);
        BARRIER; LGKM0; SB0;
        MF(alo, blo, 0, 0);
        BARRIER;

        // ===== PH6: Q3(t1) ; stage A-hi(2i+2)->buf0 =====
        RD_BHI(Bb1);
        ST_AHI(buf0, tp2);
        BARRIER; LGKM0; SB0;
        MF(alo, bhi, 0, 2);
        BARRIER;

        // ===== PH7: Q1(t1) ; stage B-lo(2i+3)->buf1 (buf1.B freed after PH6) =====
        RD_AHI(Ab1);
        ST_BLO(buf1, tp3);
        BARRIER; LGKM0; SB0;
        MF(ahi, blo, 4, 0);
        BARRIER;

        // ===== PH8: Q2(t1) ; stage B-hi(2i+3)->buf1 ; vmcnt(4) =====
        ST_BHI(buf1, tp3);
        VM4;  // retires through tile(2i+2) -> buf0 complete for next PH1
        BARRIER; SB0;
        MF(ahi, bhi, 4, 2);
        BARRIER;
    }
    asm volatile("s_waitcnt vmcnt(0)" ::: "memory");  // drain tail prefetches

    // ---- epilogue: C = acc * ax[m] + bias[n] ----
#pragma unroll
    for (int mi = 0; mi < 8; ++mi) {
#pragma unroll
        for (int j = 0; j < 4; ++j) {
            size_t mg = m0 + wm * 128 + mi * 16 + lg * 4 + j;
            float axv = ax[mg];
            float* crow = C + mg * (size_t)N + n0 + wn * 64;
#pragma unroll
            for (int ni = 0; ni < 4; ++ni) {
                int ng = ni * 16 + lr;
                crow[ng] = acc[mi][ni][j] * axv + bias[n0 + wn * 64 + ng];
            }
        }
    }
}

extern "C" void kernel_launch(void* const* d_in, const int* in_sizes, int n_in,
                              void* d_out, int out_size, void* d_ws, size_t ws_size,
                              hipStream_t stream) {
    const float* x = (const float*)d_in[0];
    const float* w = (const float*)d_in[1];
    const float* bias = (const float*)d_in[2];
    float* out = (float*)d_out;

    const int M = in_sizes[0] / K_DIM;  // 8192
    const int N = NF_DIM;               // 6400

    char* ws = (char*)d_ws;
    f16* qx = (f16*)ws;
    f16* wqt = (f16*)(ws + (size_t)M * KPAD * 2);
    float* ax = (float*)(ws + (size_t)M * KPAD * 2 + (size_t)N * KPAD * 2);
    float* sw = ax + M;

    quant_x_kernel<<<M, 256, 0, stream>>>(x, qx, ax);
    wscale_kernel<<<K_DIM, 256, 0, stream>>>(w, sw);
    wtq_kernel<<<dim3(KPAD / 64, NF_DIM / 64), 256, 0, stream>>>(w, sw, wqt);

    (void)hipFuncSetAttribute((const void*)gemm256,
                              hipFuncAttributeMaxDynamicSharedMemorySize, 131072);
    gemm256<<<(M / 256) * (N / 256), 512, 131072, stream>>>(qx, wqt, ax, bias, out, M, N);
}

// Round 4
// 240.488 us; speedup vs baseline: 1.3667x; 1.0930x over previous
//
#include <hip/hip_runtime.h>
#include <stdint.h>

typedef _Float16 f16;
typedef _Float16 f16x4 __attribute__((ext_vector_type(4)));
typedef _Float16 f16x8 __attribute__((ext_vector_type(8)));
typedef float f32x4 __attribute__((ext_vector_type(4)));

#define K_DIM 1600
#define NF_DIM 6400
#define KPAD 1664   // 26 tiles of 64
#define NKT 26
#define KPB (KPAD * 2)  // row stride in bytes = 3328

// ---------- async global->LDS 16B copy ----------
__device__ __forceinline__ void async_copy16(const void* g, void* l) {
    __builtin_amdgcn_global_load_lds(
        (const __attribute__((address_space(1))) void*)(uintptr_t)g,
        (__attribute__((address_space(3))) void*)(uint32_t)(uintptr_t)l,
        16, 0, 0);
}

// ---------- block-wide max (256 threads = 4 waves) ----------
__device__ __forceinline__ float blockMax(float v, float* sm) {
#pragma unroll
    for (int off = 32; off > 0; off >>= 1)
        v = fmaxf(v, __shfl_down(v, off, 64));
    int wid = threadIdx.x >> 6, lane = threadIdx.x & 63;
    if (lane == 0) sm[wid] = v;
    __syncthreads();
    if (threadIdx.x == 0) {
        float m = sm[0];
        for (int i = 1; i < (int)(blockDim.x >> 6); ++i) m = fmaxf(m, sm[i]);
        sm[0] = m;
    }
    __syncthreads();
    return sm[0];
}

// ---------- per-token activation quant ----------
__global__ void quant_x_kernel(const float* __restrict__ x, f16* __restrict__ qx,
                               float* __restrict__ ax) {
    __shared__ float sm[4];
    size_t row = blockIdx.x;
    const float* xr = x + row * (size_t)K_DIM;
    float m = 0.f;
    const int n4 = K_DIM >> 2;
    for (int i = threadIdx.x; i < n4; i += blockDim.x) {
        float4 v = ((const float4*)xr)[i];
        m = fmaxf(fmaxf(fmaxf(fabsf(v.x), fabsf(v.y)), fmaxf(fabsf(v.z), fabsf(v.w))), m);
    }
    m = blockMax(m, sm);
    float s = 127.0f / (m + 1e-6f);
    if (threadIdx.x == 0) ax[row] = 1.0f / (s + 1e-6f);
    f16* qr = qx + row * (size_t)KPAD;
    for (int i = threadIdx.x; i < n4; i += blockDim.x) {
        float4 v = ((const float4*)xr)[i];
        f16x4 q;
        q[0] = (f16)rintf(v.x * s);
        q[1] = (f16)rintf(v.y * s);
        q[2] = (f16)rintf(v.z * s);
        q[3] = (f16)rintf(v.w * s);
        *(f16x4*)&qr[i * 4] = q;
    }
    if (threadIdx.x < 16) {
        f16x4 z = {};
        *(f16x4*)&qr[K_DIM + threadIdx.x * 4] = z;
    }
}

// ---------- per-row weight scale ----------
__global__ void wscale_kernel(const float* __restrict__ w, float* __restrict__ sw) {
    __shared__ float sm[4];
    size_t k = blockIdx.x;
    const float* wr = w + k * (size_t)NF_DIM;
    float m = 0.f;
    const int n4 = NF_DIM >> 2;
    for (int i = threadIdx.x; i < n4; i += blockDim.x) {
        float4 v = ((const float4*)wr)[i];
        m = fmaxf(fmaxf(fmaxf(fabsf(v.x), fabsf(v.y)), fmaxf(fabsf(v.z), fabsf(v.w))), m);
    }
    m = blockMax(m, sm);
    if (threadIdx.x == 0) sw[k] = 127.0f / (m + 1e-6f);
}

// ---------- quantize + transpose weight -> wqt[N][KPAD] fp16 ----------
__global__ void wtq_kernel(const float* __restrict__ w, const float* __restrict__ sw,
                           f16* __restrict__ wqt) {
    __shared__ f16 t[64][80];
    int k0 = blockIdx.x * 64;
    int f0 = blockIdx.y * 64;
    int tid = threadIdx.x;
    if (k0 >= K_DIM) {
        int fr = tid >> 2;
        int ch = (tid & 3) << 4;
        float4 z = {};
        float4* dst = (float4*)&wqt[(size_t)(f0 + fr) * KPAD + k0 + ch];
        dst[0] = z;
        dst[1] = z;
        return;
    }
    int rr = tid >> 4;
    int cc = (tid & 15) << 2;
#pragma unroll
    for (int i = 0; i < 4; ++i) {
        int r = rr + i * 16;
        float s = sw[k0 + r];
        float inv = 1.0f / (s + 1e-6f);
        float4 v = *(const float4*)&w[(size_t)(k0 + r) * NF_DIM + f0 + cc];
        t[cc + 0][r] = (f16)(rintf(v.x * s) * inv);
        t[cc + 1][r] = (f16)(rintf(v.y * s) * inv);
        t[cc + 2][r] = (f16)(rintf(v.z * s) * inv);
        t[cc + 3][r] = (f16)(rintf(v.w * s) * inv);
    }
    __syncthreads();
    int fr = tid >> 2;
    int ch = (tid & 3) << 4;
    const float4* src = (const float4*)&t[fr][ch];
    float4* dst = (float4*)&wqt[(size_t)(f0 + fr) * KPAD + k0 + ch];
    dst[0] = src[0];
    dst[1] = src[1];
}

// ---------- 256x256 8-phase GEMM, lean addressing + vectorized epilogue ----------
__global__ __launch_bounds__(512, 1) void gemm256(
    const f16* __restrict__ A,    // [M][KPAD]
    const f16* __restrict__ Bt,   // [N][KPAD]
    const float* __restrict__ ax,
    const float* __restrict__ bias,
    float* __restrict__ C, int M, int N) {
    extern __shared__ char lds[];
    // buf b at lds + b*65536: A-lo @+0, A-hi @+16384, B-lo @+32768, B-hi @+49152

    const int tid = threadIdx.x;
    const int lane = tid & 63;
    const int wv = tid >> 6;   // 0..7
    const int wm = wv >> 2;    // 0..1
    const int wn = wv & 3;     // 0..3
    const int lr = lane & 15;
    const int lg = lane >> 4;

    const int nTn = N / 256;            // 25
    const int bid = blockIdx.x;
    const int cpx = gridDim.x >> 3;
    const int swz = (bid & 7) * cpx + (bid >> 3);
    const int tm = swz / nTn, tn = swz % nTn;
    const size_t m0 = (size_t)tm * 256, n0 = (size_t)tn * 256;

    // ---- per-thread precomputed staging pointers ----
    const int srow8 = lane >> 3;
    const int sslot = (lane & 7) ^ srow8;
    const char* pAlo = (const char*)A + (m0 + (size_t)(wv * 16 + srow8)) * KPB + sslot * 16;
    const char* pAhi = pAlo + (size_t)128 * KPB;
    const char* pBlo = (const char*)Bt + (n0 + (size_t)(wv * 16 + srow8)) * KPB + sslot * 16;
    const char* pBhi = pBlo + (size_t)128 * KPB;
    const int L0 = wv * 2048 + lane * 16;  // linear LDS dest (j=0); j=1 at +1024

#define ST(gp, t, roff)                                       \
    {                                                         \
        const char* g_ = (gp) + (size_t)(t) * 128;            \
        async_copy16(g_, lds + (roff) + L0);                  \
        async_copy16(g_ + 8 * KPB, lds + (roff) + L0 + 1024); \
    }

    // ---- per-thread LDS read constants (swizzle folded) ----
    const int swz0 = ((lg) ^ (lr & 7)) << 4;
    const int swz1 = ((4 + lg) ^ (lr & 7)) << 4;
    const int rbA = (wm * 128 + lr) * 128;
    const int rbB = 32768 + (wn * 64 + lr) * 128;

#define RD_ALO(bsel)                                                 \
    {                                                                \
        const char* p0_ = lds + (bsel) + rbA + swz0;                 \
        const char* p1_ = lds + (bsel) + rbA + swz1;                 \
        _Pragma("unroll") for (int mi_ = 0; mi_ < 4; ++mi_) {        \
            alo[mi_][0] = *(const f16x8*)(p0_ + mi_ * 2048);         \
            alo[mi_][1] = *(const f16x8*)(p1_ + mi_ * 2048);         \
        }                                                            \
    }
#define RD_AHI(bsel)                                                 \
    {                                                                \
        const char* p0_ = lds + (bsel) + rbA + swz0 + 8192;          \
        const char* p1_ = lds + (bsel) + rbA + swz1 + 8192;          \
        _Pragma("unroll") for (int mi_ = 0; mi_ < 4; ++mi_) {        \
            ahi[mi_][0] = *(const f16x8*)(p0_ + mi_ * 2048);         \
            ahi[mi_][1] = *(const f16x8*)(p1_ + mi_ * 2048);         \
        }                                                            \
    }
#define RD_BLO(bsel)                                                 \
    {                                                                \
        const char* p0_ = lds + (bsel) + rbB + swz0;                 \
        const char* p1_ = lds + (bsel) + rbB + swz1;                 \
        _Pragma("unroll") for (int ni_ = 0; ni_ < 2; ++ni_) {        \
            blo[ni_][0] = *(const f16x8*)(p0_ + ni_ * 2048);         \
            blo[ni_][1] = *(const f16x8*)(p1_ + ni_ * 2048);         \
        }                                                            \
    }
#define RD_BHI(bsel)                                                 \
    {                                                                \
        const char* p0_ = lds + (bsel) + rbB + swz0 + 4096;          \
        const char* p1_ = lds + (bsel) + rbB + swz1 + 4096;          \
        _Pragma("unroll") for (int ni_ = 0; ni_ < 2; ++ni_) {        \
            bhi[ni_][0] = *(const f16x8*)(p0_ + ni_ * 2048);         \
            bhi[ni_][1] = *(const f16x8*)(p1_ + ni_ * 2048);         \
        }                                                            \
    }

#define BARRIER __builtin_amdgcn_s_barrier()
#define LGKM0 asm volatile("s_waitcnt lgkmcnt(0)" ::: "memory")
#define SB0 __builtin_amdgcn_sched_barrier(0)
#define VM4 asm volatile("s_waitcnt vmcnt(4)" ::: "memory")

#define MF(AF, BF, R0, C0)                                                        \
    {                                                                             \
        __builtin_amdgcn_s_setprio(1);                                            \
        _Pragma("unroll") for (int mi_ = 0; mi_ < 4; ++mi_)                       \
        _Pragma("unroll") for (int ni_ = 0; ni_ < 2; ++ni_)                       \
        _Pragma("unroll") for (int kk_ = 0; kk_ < 2; ++kk_)                       \
            acc[(R0) + mi_][(C0) + ni_] = __builtin_amdgcn_mfma_f32_16x16x32_f16( \
                AF[mi_][kk_], BF[ni_][kk_], acc[(R0) + mi_][(C0) + ni_], 0, 0, 0);\
        __builtin_amdgcn_s_setprio(0);                                            \
    }

    f32x4 acc[8][4] = {};
    const int b0 = 0, b1 = 65536;

    // ---- prologue: tile0 full + tile1 B halves ----
    ST(pAlo, 0, b0 + 0);
    ST(pAhi, 0, b0 + 16384);
    ST(pBlo, 0, b0 + 32768);
    ST(pBhi, 0, b0 + 49152);
    ST(pBlo, 1, b1 + 32768);
    ST(pBhi, 1, b1 + 49152);
    VM4;
    BARRIER;

    for (int i = 0; i < NKT / 2; ++i) {
        const int t1s = 2 * i + 1;
        const int tp2 = (2 * i + 2 < NKT) ? 2 * i + 2 : NKT - 1;
        const int tp3 = (2 * i + 3 < NKT) ? 2 * i + 3 : NKT - 1;
        f16x8 alo[4][2], ahi[4][2], blo[2][2], bhi[2][2];

        // ===== PH1 =====
        RD_ALO(b0);
        RD_BLO(b0);
        ST(pAlo, t1s, b1 + 0);
        BARRIER; LGKM0; SB0;
        MF(alo, blo, 0, 0);
        BARRIER;

        // ===== PH2 =====
        RD_BHI(b0);
        ST(pAhi, t1s, b1 + 16384);
        BARRIER; LGKM0; SB0;
        MF(alo, bhi, 0, 2);
        BARRIER;

        // ===== PH3 =====
        RD_AHI(b0);
        ST(pBlo, tp2, b0 + 32768);
        BARRIER; LGKM0; SB0;
        MF(ahi, blo, 4, 0);
        BARRIER;

        // ===== PH4 =====
        ST(pBhi, tp2, b0 + 49152);
        VM4;
        BARRIER; SB0;
        MF(ahi, bhi, 4, 2);
        BARRIER;

        // ===== PH5 =====
        RD_ALO(b1);
        RD_BLO(b1);
        ST(pAlo, tp2, b0 + 0);
        BARRIER; LGKM0; SB0;
        MF(alo, blo, 0, 0);
        BARRIER;

        // ===== PH6 =====
        RD_BHI(b1);
        ST(pAhi, tp2, b0 + 16384);
        BARRIER; LGKM0; SB0;
        MF(alo, bhi, 0, 2);
        BARRIER;

        // ===== PH7 =====
        RD_AHI(b1);
        ST(pBlo, tp3, b1 + 32768);
        BARRIER; LGKM0; SB0;
        MF(ahi, blo, 4, 0);
        BARRIER;

        // ===== PH8 =====
        ST(pBhi, tp3, b1 + 49152);
        VM4;
        BARRIER; SB0;
        MF(ahi, bhi, 4, 2);
        BARRIER;
    }
    asm volatile("s_waitcnt vmcnt(0)" ::: "memory");
    __syncthreads();

    // ---- epilogue: LDS transpose -> float4 stores ----
    // per-wave region: 16 rows x 68 f32 (272B rows, <=2-way banks); 8 regions
    const float4 b4 = *(const float4*)&bias[n0 + lane * 4];
    float* wbase = (float*)lds + wv * 1088;  // 16*68
#pragma unroll
    for (int mi = 0; mi < 8; ++mi) {
        __syncthreads();  // prev readback done
#pragma unroll
        for (int ni = 0; ni < 4; ++ni)
#pragma unroll
            for (int j = 0; j < 4; ++j)
                wbase[(lg * 4 + j) * 68 + ni * 16 + lr] = acc[mi][ni][j];
        __syncthreads();
#pragma unroll
        for (int k = 0; k < 4; ++k) {
            int rr = wv * 4 + k;        // 0..31
            int wmp = rr >> 4, r16 = rr & 15;
            size_t mg = m0 + wmp * 128 + (mi & 3) * 16 + ((mi >> 2) * 0) + mi * 0 +
                        ((mi < 4) ? mi * 16 : (mi - 4) * 16) * 0;  // placeholder, fixed below
            mg = m0 + wmp * 128 + mi * 16 + r16;  // rows: wm-part via wmp, mi*16 within half? see note
            // NOTE: acc[mi] covers rows wm*128 + mi*16 (mi 0..7 spans 128 rows of this wave's half).
            // Writing wave wm=wmp region holds rows m0 + wmp*128 + mi*16 + (lg*4+j).
            float axv = ax[mg];
            int wvp = wmp * 4 + (lane >> 4);
            float4 v = *(const float4*)((const float*)lds + wvp * 1088 + r16 * 68 + (lane & 15) * 4);
            float4 o;
            o.x = v.x * axv + b4.x;
            o.y = v.y * axv + b4.y;
            o.z = v.z * axv + b4.z;
            o.w = v.w * axv + b4.w;
            *(float4*)&C[mg * (size_t)N + n0 + lane * 4] = o;
        }
    }
}

extern "C" void kernel_launch(void* const* d_in, const int* in_sizes, int n_in,
                              void* d_out, int out_size, void* d_ws, size_t ws_size,
                              hipStream_t stream) {
    const float* x = (const float*)d_in[0];
    const float* w = (const float*)d_in[1];
    const float* bias = (const float*)d_in[2];
    float* out = (float*)d_out;

    const int M = in_sizes[0] / K_DIM;  // 8192
    const int N = NF_DIM;

    char* ws = (char*)d_ws;
    f16* qx = (f16*)ws;
    f16* wqt = (f16*)(ws + (size_t)M * KPAD * 2);
    float* ax = (float*)(ws + (size_t)M * KPAD * 2 + (size_t)N * KPAD * 2);
    float* sw = ax + M;

    quant_x_kernel<<<M, 256, 0, stream>>>(x, qx, ax);
    wscale_kernel<<<K_DIM, 256, 0, stream>>>(w, sw);
    wtq_kernel<<<dim3(KPAD / 64, NF_DIM / 64), 256, 0, stream>>>(w, sw, wqt);

    (void)hipFuncSetAttribute((const void*)gemm256,
                              hipFuncAttributeMaxDynamicSharedMemorySize, 131072);
    gemm256<<<(M / 256) * (N / 256), 512, 131072, stream>>>(qx, wqt, ax, bias, out, M, N);
}